// Round 1
// baseline (15133.757 us; speedup 1.0000x reference)
//
#include <hip/hip_runtime.h>

// ---------------------------------------------------------------------------
// VRAE LSTM: B=512, T=512, HE=HD=512, L=64.
// 16 groups x 16 WGs; group = 32 batch rows, WG = 32 hidden units (128 gate cols).
// Recurrent U kept in registers as f16 MFMA B-fragments (128 VGPR/lane).
// ---------------------------------------------------------------------------

#define B_  512
#define T_  512
#define H_  512
#define NG  16
#define WPG 16
#define BPG 32
#define UPW 32

typedef _Float16 f16;
typedef _Float16 f16x8 __attribute__((ext_vector_type(8)));
typedef _Float16 f16x4 __attribute__((ext_vector_type(4)));
typedef float f32x16 __attribute__((ext_vector_type(16)));

// d_out layout (floats): mu_dec[512*512] | sg_dec[512*512] | mu_enc[512*64] | sg_enc[512*64]
#define OFF_SG_DEC 262144
#define OFF_MU_ENC 524288
#define OFF_SG_ENC 557056

__device__ __forceinline__ float sigm_(float x) { return 1.f / (1.f + __expf(-x)); }
__device__ __forceinline__ float tanh_(float x) {
  float t = fabsf(x);
  float e = __expf(2.f * t);
  float r = 1.f - 2.f / (e + 1.f);
  return x < 0.f ? -r : r;
}
__device__ __forceinline__ float softplus_(float x) {
  return fmaxf(x, 0.f) + log1pf(__expf(-fabsf(x)));
}

// ---------------------------------------------------------------------------
// Recurrent kernel.  IS_DEC=0: encoder (xin = input [B][T], gw=enc_W, gb=enc_b)
//                    IS_DEC=1: decoder (xin = zin [B][2048] incl bias, gw=dmu_W, gb=dstd_W)
// hbuf: [2][16 groups][32 rows][512 units] f16 (double-buffered h)
// flags: per-phase [16 groups][16 wgs][32 ints] (one 128B line per WG)
// ---------------------------------------------------------------------------
template <int IS_DEC>
__global__ void __launch_bounds__(256, 1)
lstm_rec(const float* __restrict__ U,     // [512][2048]
         const float* __restrict__ xin,
         const float* __restrict__ gw,
         const float* __restrict__ gb,
         f16* __restrict__ hbuf,
         float* __restrict__ accmu,
         float* __restrict__ accsg,
         int* __restrict__ flags) {
  const int bid = blockIdx.x;
  const int xcd = bid & 7, slot = bid >> 3;
  const int g = xcd * 2 + (slot >> 4);   // group 0..15 (heuristically one XCD per 2 groups)
  const int wg = slot & 15;              // hidden-slice within group
  const int tid = threadIdx.x;
  const int wave = tid >> 6, lane = tid & 63;
  const int B0 = g * BPG;
  const int U0 = wg * UPW;

  // ---------------- B fragments (U slice) into registers, f16 -----------------
  // wave w owns units U0 + 8w .. +8; tile col c = 4*uu + gate (interleaved).
  const int ccol = lane & 31, khalf = lane >> 5;
  const int uu = ccol >> 2, gate = ccol & 3;
  const int gc = gate * 512 + U0 + wave * 8 + uu;  // global gate column in [0,2048)
  f16x8 Breg[32];
#pragma unroll
  for (int ks = 0; ks < 32; ++ks) {
    f16x8 bb;
#pragma unroll
    for (int j = 0; j < 8; ++j)
      bb[j] = (f16)U[(ks * 16 + khalf * 8 + j) * 2048 + gc];
    Breg[ks] = bb;
  }

  // ---------------- per-thread elementwise mapping ----------------------------
  const int brow = tid & 31;  // batch row within group
  const int us = tid >> 5;    // unit slice 0..7 (4 units each)
  float addv[16];             // [m][gate]: ENC -> enc_b ; DEC -> zin (bias folded)
  float xw[16];               // ENC -> enc_W ; DEC unused
  float dmur[4], dstdr[4];
#pragma unroll
  for (int m = 0; m < 4; ++m) {
    const int q = us * 4 + m;
#pragma unroll
    for (int gt = 0; gt < 4; ++gt) {
      const int col = gt * 512 + U0 + q;
      if (IS_DEC) {
        addv[m * 4 + gt] = xin[(B0 + brow) * 2048 + col];
        xw[m * 4 + gt] = 0.f;
      } else {
        addv[m * 4 + gt] = gb[col];
        xw[m * 4 + gt] = gw[col];
      }
    }
    if (IS_DEC) {
      dmur[m] = gw[U0 + q];
      dstdr[m] = gb[U0 + q];
    } else {
      dmur[m] = 0.f;
      dstdr[m] = 0.f;
    }
  }

  float cst[4] = {0.f, 0.f, 0.f, 0.f};

  __shared__ float gatesLds[4 * 32 * 33];  // [wave][row][col], padded stride 33
  __shared__ float pmuLds[32 * 9];
  __shared__ float psgLds[32 * 9];

  const int arow = lane & 31;  // MFMA A row (batch row)
  int* const myflag = &flags[(g * WPG + wg) * 32];
  int* const grpflags = &flags[(g * WPG) * 32];

  for (int t = 0; t < T_; ++t) {
    // ------------------ gates = h @ U (MFMA, B in regs) ------------------
    const f16* hsrc = hbuf + (t & 1) * (NG * BPG * H_) + (B0 + arow) * H_;
    f32x16 acc;
#pragma unroll
    for (int j = 0; j < 16; ++j) acc[j] = 0.f;
#pragma unroll
    for (int ks = 0; ks < 32; ++ks) {
      f16x8 a = *(const f16x8*)(hsrc + ks * 16 + khalf * 8);
      acc = __builtin_amdgcn_mfma_f32_32x32x16_f16(a, Breg[ks], acc, 0, 0, 0);
    }
    // dump gates to LDS (C layout: col=lane&31, row=(r&3)+8*(r>>2)+4*(lane>>5))
#pragma unroll
    for (int r = 0; r < 16; ++r) {
      const int row = 4 * (lane >> 5) + (r & 3) + 8 * (r >> 2);
      gatesLds[wave * (32 * 33) + row * 33 + ccol] = acc[r];
    }
    __syncthreads();

    // ------------------ elementwise LSTM update --------------------------
    float xv = 0.f;
    if (!IS_DEC) xv = xin[(B0 + brow) * T_ + t];
    float hn[4];
#pragma unroll
    for (int m = 0; m < 4; ++m) {
      const int q = us * 4 + m;
      const int wsrc = q >> 3;
      const int uu2 = q & 7;
      float ga[4];
#pragma unroll
      for (int gt = 0; gt < 4; ++gt) {
        float v = gatesLds[wsrc * (32 * 33) + brow * 33 + uu2 * 4 + gt];
        v += addv[m * 4 + gt];
        if (!IS_DEC) v += xv * xw[m * 4 + gt];
        ga[gt] = v;
      }
      const float iv = sigm_(ga[0]);
      const float fv = sigm_(ga[1]);
      const float gv = tanh_(ga[2]);
      const float ov = sigm_(ga[3]);
      const float cn = fv * cst[m] + iv * gv;
      cst[m] = cn;
      hn[m] = ov * tanh_(cn);
    }
    // store h_new (next buffer), 4 contiguous f16 = 8B per thread
    f16x4 hv;
#pragma unroll
    for (int m = 0; m < 4; ++m) hv[m] = (f16)hn[m];
    f16* hdst = hbuf + ((t + 1) & 1) * (NG * BPG * H_) + (B0 + brow) * H_ + U0 + us * 4;
    *(f16x4*)hdst = hv;

    if (IS_DEC) {
      float pmu = 0.f, psg = 0.f;
#pragma unroll
      for (int m = 0; m < 4; ++m) {
        pmu += hn[m] * dmur[m];
        psg += hn[m] * dstdr[m];
      }
      pmuLds[brow * 9 + us] = pmu;
      psgLds[brow * 9 + us] = psg;
      __syncthreads();
      if (tid < 32) {
        float s = 0.f;
#pragma unroll
        for (int j = 0; j < 8; ++j) s += pmuLds[tid * 9 + j];
        unsafeAtomicAdd(&accmu[(B0 + tid) * T_ + t], s);
      } else if (tid < 64) {
        const int rr = tid - 32;
        float s = 0.f;
#pragma unroll
        for (int j = 0; j < 8; ++j) s += psgLds[rr * 9 + j];
        unsafeAtomicAdd(&accsg[(B0 + rr) * T_ + t], s);
      }
    }

    // ------------------ group barrier (release/acquire flags) ------------
    __syncthreads();
    if (tid == 0) {
      __hip_atomic_store(myflag, t + 1, __ATOMIC_RELEASE, __HIP_MEMORY_SCOPE_AGENT);
    }
    if (tid < WPG) {
      while (__hip_atomic_load(&grpflags[tid * 32], __ATOMIC_ACQUIRE,
                               __HIP_MEMORY_SCOPE_AGENT) < t + 1) {
      }
    }
    __syncthreads();
  }
}

// ---------------------------------------------------------------------------
// Encoder heads: mu_enc = hT@emu_W+emu_b ; sg_enc = softplus(hT@estd_W+estd_b)
// Also writes z (= mu_enc) to ws.
// ---------------------------------------------------------------------------
__global__ void enc_heads(const f16* __restrict__ h0, const float* __restrict__ emuW,
                          const float* __restrict__ emub, const float* __restrict__ estdW,
                          const float* __restrict__ estdb, float* __restrict__ out,
                          float* __restrict__ z) {
  const int b = blockIdx.x, tid = threadIdx.x;
  __shared__ float hrow[512];
  for (int k = tid; k < 512; k += 128)
    hrow[k] = (float)h0[(b >> 5) * (BPG * H_) + (b & 31) * H_ + k];
  __syncthreads();
  const int head = tid >> 6, l = tid & 63;
  const float* W = head ? estdW : emuW;
  float a = 0.f;
#pragma unroll 8
  for (int k = 0; k < 512; ++k) a += hrow[k] * W[k * 64 + l];
  if (head == 0) {
    const float v = a + emub[l];
    out[OFF_MU_ENC + b * 64 + l] = v;
    z[b * 64 + l] = v;
  } else {
    out[OFF_SG_ENC + b * 64 + l] = softplus_(a + estdb[l]);
  }
}

// ---------------------------------------------------------------------------
// Decoder prep: hd = tanh(z@dfs_W+dfs_b) -> hbuf[0];  zin = z@dec_W+dec_b
// ---------------------------------------------------------------------------
__global__ void dec_prep(const float* __restrict__ z, const float* __restrict__ dfsW,
                         const float* __restrict__ dfsb, const float* __restrict__ decW,
                         const float* __restrict__ decb, f16* __restrict__ hbuf,
                         float* __restrict__ zin) {
  const int b = blockIdx.x, tid = threadIdx.x;
  __shared__ float zl[64];
  if (tid < 64) zl[tid] = z[b * 64 + tid];
  __syncthreads();
  for (int c = tid; c < 512; c += 256) {
    float a = dfsb[c];
#pragma unroll
    for (int l = 0; l < 64; ++l) a += zl[l] * dfsW[l * 512 + c];
    hbuf[(b >> 5) * (BPG * H_) + (b & 31) * H_ + c] = (f16)tanh_(a);
  }
  for (int c = tid; c < 2048; c += 256) {
    float a = decb[c];
#pragma unroll
    for (int l = 0; l < 64; ++l) a += zl[l] * decW[l * 2048 + c];
    zin[b * 2048 + c] = a;
  }
}

// ---------------------------------------------------------------------------
// Finalize: mu_dec = acc_mu + dmu_b ; sg_dec = softplus(acc_sg + dstd_b)
// ---------------------------------------------------------------------------
__global__ void finalize_k(const float* __restrict__ accmu, const float* __restrict__ accsg,
                           const float* __restrict__ dmub, const float* __restrict__ dstdb,
                           float* __restrict__ out) {
  const int i = blockIdx.x * 256 + threadIdx.x;
  out[i] = accmu[i] + dmub[0];
  out[OFF_SG_DEC + i] = softplus_(accsg[i] + dstdb[0]);
}

// ---------------------------------------------------------------------------
extern "C" void kernel_launch(void* const* d_in, const int* in_sizes, int n_in,
                              void* d_out, int out_size, void* d_ws, size_t ws_size,
                              hipStream_t stream) {
  (void)in_sizes; (void)n_in; (void)out_size; (void)ws_size;
  const float* x     = (const float*)d_in[0];
  const float* encW  = (const float*)d_in[1];
  const float* encU  = (const float*)d_in[2];
  const float* encb  = (const float*)d_in[3];
  const float* emuW  = (const float*)d_in[4];
  const float* emub  = (const float*)d_in[5];
  const float* estdW = (const float*)d_in[6];
  const float* estdb = (const float*)d_in[7];
  const float* dfsW  = (const float*)d_in[8];
  const float* dfsb  = (const float*)d_in[9];
  const float* decW  = (const float*)d_in[10];
  const float* decU  = (const float*)d_in[11];
  const float* decb  = (const float*)d_in[12];
  const float* dmuW  = (const float*)d_in[13];
  const float* dmub  = (const float*)d_in[14];
  const float* dstdW = (const float*)d_in[15];
  const float* dstdb = (const float*)d_in[16];

  char* ws = (char*)d_ws;
  f16* hbuf    = (f16*)(ws + 0);                       // 1 MB: [2][16][32][512] f16
  float* accmu = (float*)(ws + (1u << 20));            // 1 MB
  float* accsg = (float*)(ws + (2u << 20));            // 1 MB
  int* flags   = (int*)(ws + (3u << 20));              // 64 KB (2 phases)
  float* zin   = (float*)(ws + (3u << 20) + 65536);    // 4 MB
  float* z     = (float*)(ws + (3u << 20) + 65536 + 512 * 2048 * 4);  // 128 KB
  float* out   = (float*)d_out;

  // zero h buffers, accumulators, flags (must be re-done every launch)
  hipMemsetAsync(d_ws, 0, (3u << 20) + 65536, stream);

  hipLaunchKernelGGL((lstm_rec<0>), dim3(256), dim3(256), 0, stream,
                     encU, x, encW, encb, hbuf, (float*)nullptr, (float*)nullptr, flags);
  hipLaunchKernelGGL(enc_heads, dim3(512), dim3(128), 0, stream,
                     hbuf, emuW, emub, estdW, estdb, out, z);
  hipLaunchKernelGGL(dec_prep, dim3(512), dim3(256), 0, stream,
                     z, dfsW, dfsb, decW, decb, hbuf, zin);
  hipLaunchKernelGGL((lstm_rec<1>), dim3(256), dim3(256), 0, stream,
                     decU, zin, dmuW, dstdW, hbuf, accmu, accsg, flags + 16 * 16 * 32);
  hipLaunchKernelGGL(finalize_k, dim3(1024), dim3(256), 0, stream,
                     accmu, accsg, dmub, dstdb, out);
}

// Round 3
// 7696.584 us; speedup vs baseline: 1.9663x; 1.9663x over previous
//
#include <hip/hip_runtime.h>

// ---------------------------------------------------------------------------
// VRAE LSTM: B=512, T=512, HE=HD=512, L=64.
// 16 groups x 16 WGs; group = 32 batch rows, WG = 32 hidden units (128 gate cols).
// Recurrent U kept in registers as f16 MFMA B-fragments (128 VGPR/lane, pinned).
// Cross-WG h exchange via relaxed agent-scope atomics (LLC-coherent, no L2
// wb/inv). Group h tile staged to LDS once per WG per step.
// ---------------------------------------------------------------------------

#define B_  512
#define T_  512
#define H_  512
#define NG  16
#define WPG 16
#define BPG 32
#define UPW 32

typedef _Float16 f16;
typedef _Float16 f16x8 __attribute__((ext_vector_type(8)));
typedef _Float16 f16x4 __attribute__((ext_vector_type(4)));
typedef float f32x16 __attribute__((ext_vector_type(16)));
typedef unsigned long long u64;

// d_out layout (floats): mu_dec[512*512] | sg_dec[512*512] | mu_enc[512*64] | sg_enc[512*64]
#define OFF_SG_DEC 262144
#define OFF_MU_ENC 524288
#define OFF_SG_ENC 557056

__device__ __forceinline__ float sigm_(float x) { return 1.f / (1.f + __expf(-x)); }
__device__ __forceinline__ float tanh_(float x) {
  float t = fabsf(x);
  float e = __expf(2.f * t);
  float r = 1.f - 2.f / (e + 1.f);
  return x < 0.f ? -r : r;
}
__device__ __forceinline__ float softplus_(float x) {
  return fmaxf(x, 0.f) + log1pf(__expf(-fabsf(x)));
}

// ---------------------------------------------------------------------------
// Recurrent kernel.  IS_DEC=0: encoder (xin = input [B][T], gw=enc_W, gb=enc_b)
//                    IS_DEC=1: decoder (xin = zin [B][2048] incl bias, gw=dmu_W, gb=dstd_W)
// hbuf: [2][16 groups][32 rows][512 units] f16 (double-buffered h)
// flags: per-phase [16 groups][16 wgs][32 ints] (one 128B line per WG)
// ---------------------------------------------------------------------------
template <int IS_DEC>
__global__ void __launch_bounds__(256, 1)
lstm_rec(const float* __restrict__ U,     // [512][2048]
         const float* __restrict__ xin,
         const float* __restrict__ gw,
         const float* __restrict__ gb,
         f16* __restrict__ hbuf,
         float* __restrict__ accmu,
         float* __restrict__ accsg,
         int* __restrict__ flags) {
  const int bid = blockIdx.x;
  const int g = bid >> 4;                // group 0..15
  const int wg = bid & 15;               // hidden-slice within group
  const int tid = threadIdx.x;
  const int wave = tid >> 6, lane = tid & 63;
  const int B0 = g * BPG;
  const int U0 = wg * UPW;

  // ---------------- B fragments (U slice) into registers, f16 -----------------
  // wave w owns units U0 + 8w .. +8; tile col c = 4*uu + gate (interleaved).
  const int ccol = lane & 31, khalf = lane >> 5;
  const int uu = ccol >> 2, gate = ccol & 3;
  const int gc = gate * 512 + U0 + wave * 8 + uu;  // global gate column in [0,2048)
  f16x8 Breg[32];
#pragma unroll
  for (int ks = 0; ks < 32; ++ks) {
    f16x8 bb;
#pragma unroll
    for (int j = 0; j < 8; ++j)
      bb[j] = (f16)U[(ks * 16 + khalf * 8 + j) * 2048 + gc];
    Breg[ks] = bb;
  }
  // Pin the fragments: opaque asm defeats load-rematerialization inside the
  // t-loop (round-1 showed VGPR_Count=108 => Breg was NOT resident).
#pragma unroll
  for (int ks = 0; ks < 32; ++ks) asm volatile("" : "+v"(Breg[ks]));

  // ---------------- per-thread elementwise mapping ----------------------------
  const int brow = tid & 31;  // batch row within group
  const int us = tid >> 5;    // unit slice 0..7 (4 units each)
  float addv[16];             // [m][gate]: ENC -> enc_b ; DEC -> zin (bias folded)
  float xw[16];               // ENC -> enc_W ; DEC unused
  float dmur[4], dstdr[4];
#pragma unroll
  for (int m = 0; m < 4; ++m) {
    const int q = us * 4 + m;
#pragma unroll
    for (int gt = 0; gt < 4; ++gt) {
      const int col = gt * 512 + U0 + q;
      if (IS_DEC) {
        addv[m * 4 + gt] = xin[(B0 + brow) * 2048 + col];
        xw[m * 4 + gt] = 0.f;
      } else {
        addv[m * 4 + gt] = gb[col];
        xw[m * 4 + gt] = gw[col];
      }
    }
    if (IS_DEC) {
      dmur[m] = gw[U0 + q];
      dstdr[m] = gb[U0 + q];
    } else {
      dmur[m] = 0.f;
      dstdr[m] = 0.f;
    }
  }

  float cst[4] = {0.f, 0.f, 0.f, 0.f};

  __shared__ f16 hstage[32 * 520];         // 33,280 B (stride 520 f16: +4 dword pad)
  __shared__ float gatesLds[4 * 32 * 33];  // 16,896 B [wave][row][col]
  __shared__ float pmuLds[32 * 9];
  __shared__ float psgLds[32 * 9];

  const int arow = lane & 31;  // MFMA A row (batch row)
  int* const myflag = &flags[(g * WPG + wg) * 32];
  int* const grpflags = &flags[(g * WPG) * 32];

  for (int t = 0; t < T_; ++t) {
    // ------------------ stage group h tile (32KB) -> LDS -----------------
    // LLC-coherent (relaxed agent atomic) 8B loads, coalesced.
    // 4096 u64 words total; one h row (512 f16 = 1KB) = 128 u64 words.
    const u64* hsrc64 =
        (const u64*)(hbuf + (t & 1) * (NG * BPG * H_) + B0 * H_);
    float xv = 0.f;
    if (!IS_DEC) xv = xin[(B0 + brow) * T_ + t];  // issue early, used later
#pragma unroll
    for (int i = 0; i < 16; ++i) {
      const int w = tid + i * 256;   // 8B word index, 4096 total
      const int row = w >> 7;        // 128 u64 per 512-f16 row
      const int c8 = w & 127;
      u64 v = __hip_atomic_load(hsrc64 + w, __ATOMIC_RELAXED,
                                __HIP_MEMORY_SCOPE_AGENT);
      *(u64*)&hstage[row * 520 + c8 * 4] = v;
    }
    __syncthreads();

    // ------------------ gates = h @ U (MFMA, B in regs) ------------------
    f32x16 acc;
#pragma unroll
    for (int j = 0; j < 16; ++j) acc[j] = 0.f;
#pragma unroll
    for (int ks = 0; ks < 32; ++ks) {
      f16x8 a = *(const f16x8*)&hstage[arow * 520 + ks * 16 + khalf * 8];
      acc = __builtin_amdgcn_mfma_f32_32x32x16_f16(a, Breg[ks], acc, 0, 0, 0);
    }
    // dump gates to LDS (C layout: col=lane&31, row=(r&3)+8*(r>>2)+4*(lane>>5))
#pragma unroll
    for (int r = 0; r < 16; ++r) {
      const int row = 4 * (lane >> 5) + (r & 3) + 8 * (r >> 2);
      gatesLds[wave * (32 * 33) + row * 33 + ccol] = acc[r];
    }
    __syncthreads();

    // ------------------ elementwise LSTM update --------------------------
    float hn[4];
#pragma unroll
    for (int m = 0; m < 4; ++m) {
      const int q = us * 4 + m;
      const int wsrc = q >> 3;
      const int uu2 = q & 7;
      float ga[4];
#pragma unroll
      for (int gt = 0; gt < 4; ++gt) {
        float v = gatesLds[wsrc * (32 * 33) + brow * 33 + uu2 * 4 + gt];
        v += addv[m * 4 + gt];
        if (!IS_DEC) v += xv * xw[m * 4 + gt];
        ga[gt] = v;
      }
      const float iv = sigm_(ga[0]);
      const float fv = sigm_(ga[1]);
      const float gv = tanh_(ga[2]);
      const float ov = sigm_(ga[3]);
      const float cn = fv * cst[m] + iv * gv;
      cst[m] = cn;
      hn[m] = ov * tanh_(cn);
    }
    // store h_new (next buffer) as one 8B LLC-coherent store
    union { f16x4 h4; u64 u; } cv;
#pragma unroll
    for (int m = 0; m < 4; ++m) cv.h4[m] = (f16)hn[m];
    f16* hdst = hbuf + ((t + 1) & 1) * (NG * BPG * H_) + (B0 + brow) * H_ + U0 + us * 4;
    __hip_atomic_store((u64*)hdst, cv.u, __ATOMIC_RELAXED,
                       __HIP_MEMORY_SCOPE_AGENT);

    if (IS_DEC) {
      float pmu = 0.f, psg = 0.f;
#pragma unroll
      for (int m = 0; m < 4; ++m) {
        pmu += hn[m] * dmur[m];
        psg += hn[m] * dstdr[m];
      }
      pmuLds[brow * 9 + us] = pmu;
      psgLds[brow * 9 + us] = psg;
    }

    // ------------------ release: h stores acked at LLC, then flag --------
    asm volatile("s_waitcnt vmcnt(0)" ::: "memory");
    __syncthreads();
    if (t + 1 < T_ && tid == 0)
      __hip_atomic_store(myflag, t + 1, __ATOMIC_RELAXED,
                         __HIP_MEMORY_SCOPE_AGENT);

    if (IS_DEC) {  // off the critical path: overlaps other WGs' polling
      if (tid < 32) {
        float s = 0.f;
#pragma unroll
        for (int j = 0; j < 8; ++j) s += pmuLds[tid * 9 + j];
        unsafeAtomicAdd(&accmu[(B0 + tid) * T_ + t], s);
      } else if (tid < 64) {
        const int rr = tid - 32;
        float s = 0.f;
#pragma unroll
        for (int j = 0; j < 8; ++j) s += psgLds[rr * 9 + j];
        unsafeAtomicAdd(&accsg[(B0 + rr) * T_ + t], s);
      }
    }

    // ------------------ group barrier: poll 16 flags (relaxed) -----------
    if (t + 1 < T_) {
      if (tid < WPG) {
        while (__hip_atomic_load(&grpflags[tid * 32], __ATOMIC_RELAXED,
                                 __HIP_MEMORY_SCOPE_AGENT) < t + 1) {
        }
      }
      __syncthreads();
    }
  }
}

// ---------------------------------------------------------------------------
// Encoder heads: mu_enc = hT@emu_W+emu_b ; sg_enc = softplus(hT@estd_W+estd_b)
// Also writes z (= mu_enc) to ws.
// ---------------------------------------------------------------------------
__global__ void enc_heads(const f16* __restrict__ h0, const float* __restrict__ emuW,
                          const float* __restrict__ emub, const float* __restrict__ estdW,
                          const float* __restrict__ estdb, float* __restrict__ out,
                          float* __restrict__ z) {
  const int b = blockIdx.x, tid = threadIdx.x;
  __shared__ float hrow[512];
  for (int k = tid; k < 512; k += 128)
    hrow[k] = (float)h0[b * H_ + k];
  __syncthreads();
  const int head = tid >> 6, l = tid & 63;
  const float* W = head ? estdW : emuW;
  float a = 0.f;
#pragma unroll 8
  for (int k = 0; k < 512; ++k) a += hrow[k] * W[k * 64 + l];
  if (head == 0) {
    const float v = a + emub[l];
    out[OFF_MU_ENC + b * 64 + l] = v;
    z[b * 64 + l] = v;
  } else {
    out[OFF_SG_ENC + b * 64 + l] = softplus_(a + estdb[l]);
  }
}

// ---------------------------------------------------------------------------
// Decoder prep: hd = tanh(z@dfs_W+dfs_b) -> hbuf[0];  zin = z@dec_W+dec_b
// ---------------------------------------------------------------------------
__global__ void dec_prep(const float* __restrict__ z, const float* __restrict__ dfsW,
                         const float* __restrict__ dfsb, const float* __restrict__ decW,
                         const float* __restrict__ decb, f16* __restrict__ hbuf,
                         float* __restrict__ zin) {
  const int b = blockIdx.x, tid = threadIdx.x;
  __shared__ float zl[64];
  if (tid < 64) zl[tid] = z[b * 64 + tid];
  __syncthreads();
  for (int c = tid; c < 512; c += 256) {
    float a = dfsb[c];
#pragma unroll
    for (int l = 0; l < 64; ++l) a += zl[l] * dfsW[l * 512 + c];
    hbuf[b * H_ + c] = (f16)tanh_(a);
  }
  for (int c = tid; c < 2048; c += 256) {
    float a = decb[c];
#pragma unroll
    for (int l = 0; l < 64; ++l) a += zl[l] * decW[l * 2048 + c];
    zin[b * 2048 + c] = a;
  }
}

// ---------------------------------------------------------------------------
// Finalize: mu_dec = acc_mu + dmu_b ; sg_dec = softplus(acc_sg + dstd_b)
// ---------------------------------------------------------------------------
__global__ void finalize_k(const float* __restrict__ accmu, const float* __restrict__ accsg,
                           const float* __restrict__ dmub, const float* __restrict__ dstdb,
                           float* __restrict__ out) {
  const int i = blockIdx.x * 256 + threadIdx.x;
  out[i] = accmu[i] + dmub[0];
  out[OFF_SG_DEC + i] = softplus_(accsg[i] + dstdb[0]);
}

// ---------------------------------------------------------------------------
extern "C" void kernel_launch(void* const* d_in, const int* in_sizes, int n_in,
                              void* d_out, int out_size, void* d_ws, size_t ws_size,
                              hipStream_t stream) {
  (void)in_sizes; (void)n_in; (void)out_size; (void)ws_size;
  const float* x     = (const float*)d_in[0];
  const float* encW  = (const float*)d_in[1];
  const float* encU  = (const float*)d_in[2];
  const float* encb  = (const float*)d_in[3];
  const float* emuW  = (const float*)d_in[4];
  const float* emub  = (const float*)d_in[5];
  const float* estdW = (const float*)d_in[6];
  const float* estdb = (const float*)d_in[7];
  const float* dfsW  = (const float*)d_in[8];
  const float* dfsb  = (const float*)d_in[9];
  const float* decW  = (const float*)d_in[10];
  const float* decU  = (const float*)d_in[11];
  const float* decb  = (const float*)d_in[12];
  const float* dmuW  = (const float*)d_in[13];
  const float* dmub  = (const float*)d_in[14];
  const float* dstdW = (const float*)d_in[15];
  const float* dstdb = (const float*)d_in[16];

  char* ws = (char*)d_ws;
  f16* hbuf    = (f16*)(ws + 0);                       // 1 MB: [2][512][512] f16
  float* accmu = (float*)(ws + (1u << 20));            // 1 MB
  float* accsg = (float*)(ws + (2u << 20));            // 1 MB
  int* flags   = (int*)(ws + (3u << 20));              // 64 KB (2 phases)
  float* zin   = (float*)(ws + (3u << 20) + 65536);    // 4 MB
  float* z     = (float*)(ws + (3u << 20) + 65536 + 512 * 2048 * 4);  // 128 KB
  float* out   = (float*)d_out;

  // zero h buffers, accumulators, flags (must be re-done every launch)
  hipMemsetAsync(d_ws, 0, (3u << 20) + 65536, stream);

  hipLaunchKernelGGL((lstm_rec<0>), dim3(256), dim3(256), 0, stream,
                     encU, x, encW, encb, hbuf, (float*)nullptr, (float*)nullptr, flags);
  hipLaunchKernelGGL(enc_heads, dim3(512), dim3(128), 0, stream,
                     hbuf, emuW, emub, estdW, estdb, out, z);
  hipLaunchKernelGGL(dec_prep, dim3(512), dim3(256), 0, stream,
                     z, dfsW, dfsb, decW, decb, hbuf, zin);
  hipLaunchKernelGGL((lstm_rec<1>), dim3(256), dim3(256), 0, stream,
                     decU, zin, dmuW, dstdW, hbuf, accmu, accsg, flags + 16 * 16 * 32);
  hipLaunchKernelGGL(finalize_k, dim3(1024), dim3(256), 0, stream,
                     accmu, accsg, dmub, dstdb, out);
}